// Round 1
// baseline (2373.593 us; speedup 1.0000x reference)
//
#include <hip/hip_runtime.h>
#include <hip/hip_bf16.h>
#include <cstdint>
#include <cstddef>

#define NN 4096
#define SINK_ITERS 20
#define EPSV 1e-6f

typedef unsigned short u16;
typedef __attribute__((ext_vector_type(8))) short bf16x8;
typedef __attribute__((ext_vector_type(4))) float f32x4;

__device__ __forceinline__ float bf2f(u16 u) {
  union { unsigned int i; float f; } x; x.i = ((unsigned int)u) << 16; return x.f;
}
__device__ __forceinline__ u16 f2bf(float f) {
  union { float f; unsigned int i; } x; x.f = f;
  unsigned int i = x.i;
  unsigned int r = i + 0x7FFFu + ((i >> 16) & 1u);   // round-to-nearest-even
  return (u16)(r >> 16);
}

typedef const __attribute__((address_space(1))) unsigned int* gas_p;
typedef __attribute__((address_space(3))) unsigned int* las_p;
__device__ __forceinline__ void gload16(const void* g, void* l) {
  __builtin_amdgcn_global_load_lds((gas_p)g, (las_p)l, 16, 0, 0);
}

// ---------------- init u=v=1, S=T=0 ----------------
__global__ void k_init(float* __restrict__ u, float* __restrict__ v,
                       float* __restrict__ S, float* __restrict__ T) {
  int i = blockIdx.x * 256 + threadIdx.x;
  if (i < NN) { u[i] = 1.f; v[i] = 1.f; S[i] = 0.f; T[i] = 0.f; }
}

// ---------------- K = bf16(exp(W)) ----------------
__global__ void k_expbf(const float* __restrict__ W, u16* __restrict__ Kb) {
  long idx = ((long)blockIdx.x * 256 + threadIdx.x) * 8;
  f32x4 a = *(const f32x4*)(W + idx);
  f32x4 b = *(const f32x4*)(W + idx + 4);
  bf16x8 r;
#pragma unroll
  for (int c = 0; c < 4; ++c) r[c] = (short)f2bf(expf(a[c]));
#pragma unroll
  for (int c = 0; c < 4; ++c) r[4 + c] = (short)f2bf(expf(b[c]));
  *(bf16x8*)(Kb + idx) = r;
}

// ---------------- xb = bf16(x) ----------------
__global__ void k_f2bf(const float* __restrict__ X, u16* __restrict__ Xb, long n8) {
  long stride = (long)gridDim.x * blockDim.x;
  for (long i = (long)blockIdx.x * blockDim.x + threadIdx.x; i < n8; i += stride) {
    long idx = i * 8;
    f32x4 a = *(const f32x4*)(X + idx);
    f32x4 b = *(const f32x4*)(X + idx + 4);
    bf16x8 r;
#pragma unroll
    for (int c = 0; c < 4; ++c) r[c] = (short)f2bf(a[c]);
#pragma unroll
    for (int c = 0; c < 4; ++c) r[4 + c] = (short)f2bf(b[c]);
    *(bf16x8*)(Xb + idx) = r;
  }
}

// ---------------- S_j += sum_i u_i * K_ij  (512 blocks: jb in 0..1, ib in 0..255) ----------------
__global__ void k_colsum(const u16* __restrict__ Kb, const float* __restrict__ u,
                         float* __restrict__ S) {
  int jb = blockIdx.x & 1, ib = blockIdx.x >> 1;
  int j0 = jb * 2048 + threadIdx.x * 8;
  int i0 = ib * 16;
  float acc[8] = {0.f, 0.f, 0.f, 0.f, 0.f, 0.f, 0.f, 0.f};
#pragma unroll
  for (int r = 0; r < 16; ++r) {
    int i = i0 + r;
    float ui = u[i];
    bf16x8 kv = *(const bf16x8*)(Kb + (size_t)i * NN + j0);
#pragma unroll
    for (int c = 0; c < 8; ++c) acc[c] += ui * bf2f((u16)kv[c]);
  }
#pragma unroll
  for (int c = 0; c < 8; ++c) atomicAdd(&S[j0 + c], acc[c]);
}

// ---------------- T_i = sum_j K_ij * v'_j ; v' computed on the fly from (v,S) ----------------
__global__ void k_rowsum(const u16* __restrict__ Kb, const float* __restrict__ v,
                         const float* __restrict__ S, float* __restrict__ T) {
  int warp = threadIdx.x >> 6, lane = threadIdx.x & 63;
  int row = blockIdx.x * 4 + warp;
  const u16* kr = Kb + (size_t)row * NN;
  float acc = 0.f;
#pragma unroll
  for (int itn = 0; itn < 8; ++itn) {
    int j = itn * 512 + lane * 8;
    bf16x8 kv = *(const bf16x8*)(kr + j);
    f32x4 v0 = *(const f32x4*)(v + j);
    f32x4 v1 = *(const f32x4*)(v + j + 4);
    f32x4 s0 = *(const f32x4*)(S + j);
    f32x4 s1 = *(const f32x4*)(S + j + 4);
#pragma unroll
    for (int c = 0; c < 4; ++c) {
      float vn = v0[c] / (v0[c] * s0[c] + EPSV);
      acc += bf2f((u16)kv[c]) * vn;
    }
#pragma unroll
    for (int c = 0; c < 4; ++c) {
      float vn = v1[c] / (v1[c] * s1[c] + EPSV);
      acc += bf2f((u16)kv[4 + c]) * vn;
    }
  }
#pragma unroll
  for (int off = 32; off > 0; off >>= 1) acc += __shfl_down(acc, off, 64);
  if (lane == 0) T[row] = acc;
}

// ---------------- finalize: v <- v/(v*S+eps); u <- u/(u*T+eps); zero S,T ----------------
__global__ void k_update(float* __restrict__ u, float* __restrict__ v,
                         float* __restrict__ S, float* __restrict__ T) {
  int i = blockIdx.x * 256 + threadIdx.x;
  if (i < NN) {
    float vi = v[i], Si = S[i];
    v[i] = vi / (vi * Si + EPSV);
    S[i] = 0.f;
    float ui = u[i], Ti = T[i];
    u[i] = ui / (ui * Ti + EPSV);
    T[i] = 0.f;
  }
}

// ---------------- Pt[j][i] = bf16(u_i * exp(W_ij) * v_j)  (64x64 tiles, LDS transpose) ----------------
__global__ void k_matP(const float* __restrict__ W, const float* __restrict__ u,
                       const float* __restrict__ v, u16* __restrict__ Pt) {
  __shared__ float tile[64 * 65];
  int bx = blockIdx.x & 63, by = blockIdx.x >> 6;  // bx: j-tile, by: i-tile
  int tx = threadIdx.x & 63, ty = threadIdx.x >> 6;
  float vj = v[bx * 64 + tx];
#pragma unroll
  for (int r = 0; r < 16; ++r) {
    int il = r * 4 + ty;
    int i = by * 64 + il;
    float w = W[(size_t)i * NN + bx * 64 + tx];
    tile[il * 65 + tx] = u[i] * expf(w) * vj;
  }
  __syncthreads();
#pragma unroll
  for (int r = 0; r < 16; ++r) {
    int jl = r * 4 + ty;
    Pt[(size_t)(bx * 64 + jl) * NN + by * 64 + tx] = f2bf(tile[tx * 65 + jl]);
  }
}

// ---------------- GEMM: C[M=16384][4096] f32 = A_bf16[M][4096] @ Pt^T, m97 128x128 structure ----------------
#define BM 128
#define BN 128
#define BK 32
#define NT (NN / BK)

__global__ __launch_bounds__(256) void k_gemm(const u16* __restrict__ A,
                                              const u16* __restrict__ Bt,
                                              float* __restrict__ C) {
  __shared__ __align__(16) u16 lA[2][BM * BK];
  __shared__ __align__(16) u16 lB[2][BN * BK];

  int bid = blockIdx.x;                       // 4096 blocks
  int swz = (bid & 7) * 512 + (bid >> 3);     // XCD-aware swizzle (bijective: 4096 % 8 == 0)
  int bm = swz >> 5, bn = swz & 31;           // 128 x 32 tiles

  int tid = threadIdx.x;
  int lane = tid & 63, w = tid >> 6;          // 4 waves
  int wm = (w >> 1) * 64, wn = (w & 1) * 64;
  size_t m0 = (size_t)bm * BM, n0 = (size_t)bn * BN;

  f32x4 acc[4][4];
#pragma unroll
  for (int a = 0; a < 4; ++a)
#pragma unroll
    for (int b = 0; b < 4; ++b) acc[a][b] = (f32x4){0.f, 0.f, 0.f, 0.f};

  int srow = tid >> 2;            // 0..63
  int skc = (tid & 3) * 8;        // 0,8,16,24

  auto stage = [&](int buf, int t) {
    int k0 = t * BK;
#pragma unroll
    for (int it = 0; it < 2; ++it) {
      int row = it * 64 + srow;
      gload16(A + (m0 + row) * NN + k0 + skc, &lA[buf][row * BK + skc]);
      gload16(Bt + (n0 + row) * NN + k0 + skc, &lB[buf][row * BK + skc]);
    }
  };

  stage(0, 0);
  __syncthreads();

  int arow = wm + (lane & 15);
  int brow = wn + (lane & 15);
  int kc = (lane >> 4) * 8;

  for (int t = 0; t < NT; ++t) {
    int cur = t & 1;
    if (t < NT - 1) stage(cur ^ 1, t + 1);
    bf16x8 af[4], bfr[4];
#pragma unroll
    for (int f = 0; f < 4; ++f) {
      af[f] = *(const bf16x8*)&lA[cur][(arow + f * 16) * BK + kc];
      bfr[f] = *(const bf16x8*)&lB[cur][(brow + f * 16) * BK + kc];
    }
#pragma unroll
    for (int fm = 0; fm < 4; ++fm)
#pragma unroll
      for (int fn = 0; fn < 4; ++fn)
        acc[fm][fn] = __builtin_amdgcn_mfma_f32_16x16x32_bf16(af[fm], bfr[fn], acc[fm][fn], 0, 0, 0);
    __syncthreads();
  }

#pragma unroll
  for (int fm = 0; fm < 4; ++fm) {
    int r0 = wm + fm * 16 + (lane >> 4) * 4;
#pragma unroll
    for (int fn = 0; fn < 4; ++fn) {
      int c0 = wn + fn * 16 + (lane & 15);
#pragma unroll
      for (int i = 0; i < 4; ++i) {
        C[(m0 + r0 + i) * NN + n0 + c0] = acc[fm][fn][i];
      }
    }
  }
}

extern "C" void kernel_launch(void* const* d_in, const int* in_sizes, int n_in,
                              void* d_out, int out_size, void* d_ws, size_t ws_size,
                              hipStream_t stream) {
  const float* x = (const float*)d_in[0];   // [4,4096,4096] f32
  const float* W = (const float*)d_in[1];   // [4096,4096] f32
  float* out = (float*)d_out;               // [4,4096,4096] f32

  char* ws = (char*)d_ws;
  const size_t XB_OFF = 0;                      // 128 MB
  const size_t PT_OFF = 134217728;              // 32 MB
  const size_t KB_OFF = 167772160;              // 32 MB
  const size_t VEC_OFF = 201326592;             // 4 x 16 KB
  if (ws_size < VEC_OFF + 4 * (size_t)NN * sizeof(float)) return;

  u16* xb = (u16*)(ws + XB_OFF);
  u16* Ptb = (u16*)(ws + PT_OFF);
  u16* Kb = (u16*)(ws + KB_OFF);
  float* u = (float*)(ws + VEC_OFF);
  float* v = u + NN;
  float* S = v + NN;
  float* T = S + NN;

  k_init<<<16, 256, 0, stream>>>(u, v, S, T);
  k_expbf<<<8192, 256, 0, stream>>>(W, Kb);
  k_f2bf<<<2048, 256, 0, stream>>>(x, xb, (long)out_size / 8);

  for (int it = 0; it < SINK_ITERS; ++it) {
    k_colsum<<<512, 256, 0, stream>>>(Kb, u, S);
    k_rowsum<<<1024, 256, 0, stream>>>(Kb, v, S, T);
    k_update<<<16, 256, 0, stream>>>(u, v, S, T);
  }

  k_matP<<<4096, 256, 0, stream>>>(W, u, v, Ptb);
  k_gemm<<<4096, 256, 0, stream>>>(xb, Ptb, out);
}

// Round 2
// 1724.367 us; speedup vs baseline: 1.3765x; 1.3765x over previous
//
#include <hip/hip_runtime.h>
#include <hip/hip_bf16.h>
#include <cstdint>
#include <cstddef>

#define NN 4096
#define SINK_ITERS 20
#define EPSV 1e-6f

typedef unsigned short u16;
typedef __attribute__((ext_vector_type(8))) short bf16x8;
typedef __attribute__((ext_vector_type(4))) short bf16x4;
typedef __attribute__((ext_vector_type(4))) float f32x4;

__device__ __forceinline__ float bf2f(u16 u) {
  union { unsigned int i; float f; } x; x.i = ((unsigned int)u) << 16; return x.f;
}
__device__ __forceinline__ u16 f2bf(float f) {
  union { float f; unsigned int i; } x; x.f = f;
  unsigned int i = x.i;
  unsigned int r = i + 0x7FFFu + ((i >> 16) & 1u);   // round-to-nearest-even
  return (u16)(r >> 16);
}

typedef const __attribute__((address_space(1))) unsigned int* gas_p;
typedef __attribute__((address_space(3))) unsigned int* las_p;
__device__ __forceinline__ void gload16(const void* g, void* l) {
  __builtin_amdgcn_global_load_lds((gas_p)g, (las_p)l, 16, 0, 0);
}

// ================= persistent cooperative-style Sinkhorn =================
// 256 wgs (16x16), each owns a 256x256 tile of K=exp(W) in LDS (1 wg/CU).
// Hand-rolled grid barrier (device-scope atomics); monotonic counter, reset
// via hipMemsetAsync before each launch.

#define SINK_WGS 256
#define SINK_SMEM (131072 + 1024 + 1024 + 8192)

__device__ __forceinline__ void gsync(unsigned* bar, int round) {
  __syncthreads();
  if (threadIdx.x == 0) {
    __threadfence();                       // release
    atomicAdd(bar, 1u);
    unsigned goal = (unsigned)(round + 1) * SINK_WGS;
    long spin = 0;
    unsigned vv;
    do {
      vv = __hip_atomic_load(bar, __ATOMIC_RELAXED, __HIP_MEMORY_SCOPE_AGENT);
    } while (vv < goal && ++spin < 200000000L);
    __threadfence();                       // acquire
  }
  __syncthreads();
}

__global__ __launch_bounds__(512) void k_sinkhorn(
    const float* __restrict__ W, float* __restrict__ ubuf, float* __restrict__ vbuf,
    float* __restrict__ Spart, float* __restrict__ Tpart, unsigned* bar) {
  extern __shared__ char smem[];
  u16* Kt = (u16*)smem;                       // [256][256] bf16
  float* u_loc = (float*)(smem + 131072);     // [256]
  float* v_loc = u_loc + 256;                 // [256]
  float* red = v_loc + 256;                   // [8][256]

  int wg = blockIdx.x;
  int a = wg >> 4, b = wg & 15;               // row-stripe, col-stripe
  int i0 = a * 256, j0 = b * 256;
  int t = threadIdx.x;
  int lane = t & 63, wv = t >> 6;
  int cg = t & 31;                            // col-group of 8 (phaseA/B units)

  // ---- stage exp(W) tile into LDS (each wave reads whole 1KB rows) ----
#pragma unroll
  for (int k = 0; k < 32; ++k) {
    int q = t + 512 * k;            // 0..16383
    int il = q >> 6;                // 0..255
    int jc = (q & 63) << 2;         // 0..252 step 4
    f32x4 wvv = *(const f32x4*)(W + (size_t)(i0 + il) * NN + (j0 + jc));
    bf16x4 r;
#pragma unroll
    for (int c = 0; c < 4; ++c) r[c] = (short)f2bf(expf(wvv[c]));
    *(bf16x4*)(Kt + il * 256 + jc) = r;
  }
  // v_0 = ones (visible to B(0) after the grid sync at end of A(0))
  if (a == 0 && t < 256) vbuf[j0 + t] = 1.f;
  __syncthreads();

  int rnd = 0;
  for (int it = 0; it < SINK_ITERS; ++it) {
    // ================= Phase A: u update + partial colsum =================
    if (t < 256) {
      float un;
      if (it == 0) {
        un = 1.f;
      } else {
        float Ts = 0.f;
#pragma unroll
        for (int p = 0; p < 16; ++p) Ts += Tpart[p * NN + i0 + t];
        float uo = ubuf[(it & 1) * NN + i0 + t];
        un = uo / (uo * Ts + EPSV);
      }
      u_loc[t] = un;
      if (b == 0) ubuf[((it + 1) & 1) * NN + i0 + t] = un;
    }
    __syncthreads();

    float acc[8] = {0.f, 0.f, 0.f, 0.f, 0.f, 0.f, 0.f, 0.f};
#pragma unroll
    for (int k = 0; k < 16; ++k) {
      int row = (t >> 5) + 16 * k;
      bf16x8 kv = *(const bf16x8*)(Kt + row * 256 + cg * 8);
      float ui = u_loc[row];
#pragma unroll
      for (int c = 0; c < 8; ++c) acc[c] += ui * bf2f((u16)kv[c]);
    }
#pragma unroll
    for (int c = 0; c < 8; ++c) acc[c] += __shfl_xor(acc[c], 32, 64);
    if (lane < 32) {
#pragma unroll
      for (int c = 0; c < 8; ++c) red[wv * 256 + cg * 8 + c] = acc[c];
    }
    __syncthreads();
    if (t < 256) {
      float s = 0.f;
#pragma unroll
      for (int w = 0; w < 8; ++w) s += red[w * 256 + t];
      Spart[a * NN + j0 + t] = s;
    }
    gsync(bar, rnd++);

    // ================= Phase B: v update + partial rowsum =================
    if (t < 256) {
      float Ss = 0.f;
#pragma unroll
      for (int p = 0; p < 16; ++p) Ss += Spart[p * NN + j0 + t];
      float vo = vbuf[(it & 1) * NN + j0 + t];
      float vn = vo / (vo * Ss + EPSV);
      v_loc[t] = vn;
      if (a == 0) vbuf[((it + 1) & 1) * NN + j0 + t] = vn;
    }
    __syncthreads();

    f32x4 va = *(const f32x4*)(v_loc + cg * 8);
    f32x4 vb2 = *(const f32x4*)(v_loc + cg * 8 + 4);
    float tr[16];
#pragma unroll
    for (int k = 0; k < 16; ++k) {
      int row = (t >> 5) + 16 * k;
      bf16x8 kv = *(const bf16x8*)(Kt + row * 256 + cg * 8);
      float s = 0.f;
#pragma unroll
      for (int c = 0; c < 4; ++c) s += bf2f((u16)kv[c]) * va[c];
#pragma unroll
      for (int c = 0; c < 4; ++c) s += bf2f((u16)kv[4 + c]) * vb2[c];
      tr[k] = s;
    }
#pragma unroll
    for (int k = 0; k < 16; ++k) {
#pragma unroll
      for (int d = 1; d <= 16; d <<= 1) tr[k] += __shfl_xor(tr[k], d, 64);
    }
    if (lane == 0 || lane == 32) {
#pragma unroll
      for (int k = 0; k < 16; ++k) red[(t >> 5) + 16 * k] = tr[k];
    }
    __syncthreads();
    if (t < 256) Tpart[b * NN + i0 + t] = red[t];
    gsync(bar, rnd++);
  }

  // ---- final u_20 -> ubuf[1]  (v_20 already at vbuf[0]) ----
  if (t < 256) {
    float Ts = 0.f;
#pragma unroll
    for (int p = 0; p < 16; ++p) Ts += Tpart[p * NN + i0 + t];
    float uo = ubuf[0 * NN + i0 + t];
    float un = uo / (uo * Ts + EPSV);
    if (b == 0) ubuf[1 * NN + i0 + t] = un;
  }
}

// ================= legacy fallback path (round-1 kernels) =================
__global__ void k_init(float* __restrict__ u, float* __restrict__ v,
                       float* __restrict__ S, float* __restrict__ T) {
  int i = blockIdx.x * 256 + threadIdx.x;
  if (i < NN) { u[i] = 1.f; v[i] = 1.f; S[i] = 0.f; T[i] = 0.f; }
}

__global__ void k_expbf(const float* __restrict__ W, u16* __restrict__ Kb) {
  long idx = ((long)blockIdx.x * 256 + threadIdx.x) * 8;
  f32x4 a = *(const f32x4*)(W + idx);
  f32x4 b = *(const f32x4*)(W + idx + 4);
  bf16x8 r;
#pragma unroll
  for (int c = 0; c < 4; ++c) r[c] = (short)f2bf(expf(a[c]));
#pragma unroll
  for (int c = 0; c < 4; ++c) r[4 + c] = (short)f2bf(expf(b[c]));
  *(bf16x8*)(Kb + idx) = r;
}

__global__ void k_f2bf(const float* __restrict__ X, u16* __restrict__ Xb, long n8) {
  long stride = (long)gridDim.x * blockDim.x;
  for (long i = (long)blockIdx.x * blockDim.x + threadIdx.x; i < n8; i += stride) {
    long idx = i * 8;
    f32x4 a = *(const f32x4*)(X + idx);
    f32x4 b = *(const f32x4*)(X + idx + 4);
    bf16x8 r;
#pragma unroll
    for (int c = 0; c < 4; ++c) r[c] = (short)f2bf(a[c]);
#pragma unroll
    for (int c = 0; c < 4; ++c) r[4 + c] = (short)f2bf(b[c]);
    *(bf16x8*)(Xb + idx) = r;
  }
}

__global__ void k_colsum(const u16* __restrict__ Kb, const float* __restrict__ u,
                         float* __restrict__ S) {
  int jb = blockIdx.x & 1, ib = blockIdx.x >> 1;
  int j0 = jb * 2048 + threadIdx.x * 8;
  int i0 = ib * 16;
  float acc[8] = {0.f, 0.f, 0.f, 0.f, 0.f, 0.f, 0.f, 0.f};
#pragma unroll
  for (int r = 0; r < 16; ++r) {
    int i = i0 + r;
    float ui = u[i];
    bf16x8 kv = *(const bf16x8*)(Kb + (size_t)i * NN + j0);
#pragma unroll
    for (int c = 0; c < 8; ++c) acc[c] += ui * bf2f((u16)kv[c]);
  }
#pragma unroll
  for (int c = 0; c < 8; ++c) atomicAdd(&S[j0 + c], acc[c]);
}

__global__ void k_rowsum(const u16* __restrict__ Kb, const float* __restrict__ v,
                         const float* __restrict__ S, float* __restrict__ T) {
  int warp = threadIdx.x >> 6, lane = threadIdx.x & 63;
  int row = blockIdx.x * 4 + warp;
  const u16* kr = Kb + (size_t)row * NN;
  float acc = 0.f;
#pragma unroll
  for (int itn = 0; itn < 8; ++itn) {
    int j = itn * 512 + lane * 8;
    bf16x8 kv = *(const bf16x8*)(kr + j);
    f32x4 v0 = *(const f32x4*)(v + j);
    f32x4 v1 = *(const f32x4*)(v + j + 4);
    f32x4 s0 = *(const f32x4*)(S + j);
    f32x4 s1 = *(const f32x4*)(S + j + 4);
#pragma unroll
    for (int c = 0; c < 4; ++c) acc += bf2f((u16)kv[c]) * (v0[c] / (v0[c] * s0[c] + EPSV));
#pragma unroll
    for (int c = 0; c < 4; ++c) acc += bf2f((u16)kv[4 + c]) * (v1[c] / (v1[c] * s1[c] + EPSV));
  }
#pragma unroll
  for (int off = 32; off > 0; off >>= 1) acc += __shfl_down(acc, off, 64);
  if (lane == 0) T[row] = acc;
}

__global__ void k_update(float* __restrict__ u, float* __restrict__ v,
                         float* __restrict__ S, float* __restrict__ T) {
  int i = blockIdx.x * 256 + threadIdx.x;
  if (i < NN) {
    float vi = v[i], Si = S[i];
    v[i] = vi / (vi * Si + EPSV);
    S[i] = 0.f;
    float ui = u[i], Ti = T[i];
    u[i] = ui / (ui * Ti + EPSV);
    T[i] = 0.f;
  }
}

// ---------------- Pt[j][i] = bf16(u_i * exp(W_ij) * v_j) ----------------
__global__ void k_matP(const float* __restrict__ W, const float* __restrict__ u,
                       const float* __restrict__ v, u16* __restrict__ Pt) {
  __shared__ float tile[64 * 65];
  int bx = blockIdx.x & 63, by = blockIdx.x >> 6;
  int tx = threadIdx.x & 63, ty = threadIdx.x >> 6;
  float vj = v[bx * 64 + tx];
#pragma unroll
  for (int r = 0; r < 16; ++r) {
    int il = r * 4 + ty;
    int i = by * 64 + il;
    float w = W[(size_t)i * NN + bx * 64 + tx];
    tile[il * 65 + tx] = u[i] * expf(w) * vj;
  }
  __syncthreads();
#pragma unroll
  for (int r = 0; r < 16; ++r) {
    int jl = r * 4 + ty;
    Pt[(size_t)(bx * 64 + jl) * NN + by * 64 + tx] = f2bf(tile[tx * 65 + jl]);
  }
}

// ---------------- GEMM: C[16384][4096] = A_bf16 @ Pt^T (m97 128x128) ----------------
#define BM 128
#define BN 128
#define BK 32
#define NT (NN / BK)

__global__ __launch_bounds__(256) void k_gemm(const u16* __restrict__ A,
                                              const u16* __restrict__ Bt,
                                              float* __restrict__ C) {
  __shared__ __align__(16) u16 lA[2][BM * BK];
  __shared__ __align__(16) u16 lB[2][BN * BK];

  int bid = blockIdx.x;
  int swz = (bid & 7) * 512 + (bid >> 3);
  int bm = swz >> 5, bn = swz & 31;

  int tid = threadIdx.x;
  int lane = tid & 63, w = tid >> 6;
  int wm = (w >> 1) * 64, wn = (w & 1) * 64;
  size_t m0 = (size_t)bm * BM, n0 = (size_t)bn * BN;

  f32x4 acc[4][4];
#pragma unroll
  for (int a = 0; a < 4; ++a)
#pragma unroll
    for (int b = 0; b < 4; ++b) acc[a][b] = (f32x4){0.f, 0.f, 0.f, 0.f};

  int srow = tid >> 2;
  int skc = (tid & 3) * 8;

  auto stage = [&](int buf, int t) {
    int k0 = t * BK;
#pragma unroll
    for (int it = 0; it < 2; ++it) {
      int row = it * 64 + srow;
      gload16(A + (m0 + row) * NN + k0 + skc, &lA[buf][row * BK + skc]);
      gload16(Bt + (n0 + row) * NN + k0 + skc, &lB[buf][row * BK + skc]);
    }
  };

  stage(0, 0);
  __syncthreads();

  int arow = wm + (lane & 15);
  int brow = wn + (lane & 15);
  int kc = (lane >> 4) * 8;

  for (int t = 0; t < NT; ++t) {
    int cur = t & 1;
    if (t < NT - 1) stage(cur ^ 1, t + 1);
    bf16x8 af[4], bfr[4];
#pragma unroll
    for (int f = 0; f < 4; ++f) {
      af[f] = *(const bf16x8*)&lA[cur][(arow + f * 16) * BK + kc];
      bfr[f] = *(const bf16x8*)&lB[cur][(brow + f * 16) * BK + kc];
    }
#pragma unroll
    for (int fm = 0; fm < 4; ++fm)
#pragma unroll
      for (int fn = 0; fn < 4; ++fn)
        acc[fm][fn] = __builtin_amdgcn_mfma_f32_16x16x32_bf16(af[fm], bfr[fn], acc[fm][fn], 0, 0, 0);
    __syncthreads();
  }

#pragma unroll
  for (int fm = 0; fm < 4; ++fm) {
    int r0 = wm + fm * 16 + (lane >> 4) * 4;
#pragma unroll
    for (int fn = 0; fn < 4; ++fn) {
      int c0 = wn + fn * 16 + (lane & 15);
#pragma unroll
      for (int i = 0; i < 4; ++i) {
        C[(m0 + r0 + i) * NN + n0 + c0] = acc[fm][fn][i];
      }
    }
  }
}

extern "C" void kernel_launch(void* const* d_in, const int* in_sizes, int n_in,
                              void* d_out, int out_size, void* d_ws, size_t ws_size,
                              hipStream_t stream) {
  const float* x = (const float*)d_in[0];   // [4,4096,4096] f32
  const float* W = (const float*)d_in[1];   // [4096,4096] f32
  float* out = (float*)d_out;               // [4,4096,4096] f32

  char* ws = (char*)d_ws;
  const size_t XB_OFF = 0;                      // 128 MB
  const size_t PT_OFF = 134217728;              // 32 MB
  const size_t KB_OFF = 167772160;              // 32 MB (legacy Kb / coop scratch)
  const size_t VEC_OFF = 201326592;             // legacy u,v,S,T
  if (ws_size < VEC_OFF + 4 * (size_t)NN * sizeof(float)) return;

  u16* xb = (u16*)(ws + XB_OFF);
  u16* Ptb = (u16*)(ws + PT_OFF);
  u16* Kb = (u16*)(ws + KB_OFF);
  float* lu = (float*)(ws + VEC_OFF);
  float* lv = lu + NN;
  float* lS = lv + NN;
  float* lT = lS + NN;

  // coop scratch overlaps the (unused-in-coop-path) Kb region
  float* ub = (float*)(ws + KB_OFF);            // [2][4096]
  float* vb = ub + 2 * NN;                      // [2][4096]
  float* Sp = vb + 2 * NN;                      // [16][4096]
  float* Tp = Sp + 16 * NN;                     // [16][4096]
  unsigned* bar = (unsigned*)(Tp + 16 * NN);

  k_f2bf<<<2048, 256, 0, stream>>>(x, xb, (long)out_size / 8);

  bool coop = true;
  int dev = 0;
  hipDeviceProp_t prop;
  if (hipGetDevice(&dev) != hipSuccess) coop = false;
  else if (hipGetDeviceProperties(&prop, dev) != hipSuccess) coop = false;
  else if (prop.multiProcessorCount < SINK_WGS) coop = false;
  if (coop && hipFuncSetAttribute((const void*)k_sinkhorn,
                                  hipFuncAttributeMaxDynamicSharedMemorySize,
                                  SINK_SMEM) != hipSuccess)
    coop = false;

  if (coop) {
    hipMemsetAsync(bar, 0, sizeof(unsigned), stream);
    k_sinkhorn<<<SINK_WGS, 512, SINK_SMEM, stream>>>(W, ub, vb, Sp, Tp, bar);
    if (hipGetLastError() != hipSuccess) coop = false;
  }

  const float* uP;
  const float* vP;
  if (coop) {
    uP = ub + NN;   // u_20
    vP = vb;        // v_20
  } else {
    k_init<<<16, 256, 0, stream>>>(lu, lv, lS, lT);
    k_expbf<<<8192, 256, 0, stream>>>(W, Kb);
    for (int it = 0; it < SINK_ITERS; ++it) {
      k_colsum<<<512, 256, 0, stream>>>(Kb, lu, lS);
      k_rowsum<<<1024, 256, 0, stream>>>(Kb, lv, lS, lT);
      k_update<<<16, 256, 0, stream>>>(lu, lv, lS, lT);
    }
    uP = lu;
    vP = lv;
  }

  k_matP<<<4096, 256, 0, stream>>>(W, uP, vP, Ptb);
  k_gemm<<<4096, 256, 0, stream>>>(xb, Ptb, out);
}

// Round 3
// 1347.345 us; speedup vs baseline: 1.7617x; 1.2798x over previous
//
#include <hip/hip_runtime.h>
#include <hip/hip_bf16.h>
#include <cstdint>
#include <cstddef>

#define NN 4096
#define SINK_ITERS 20
#define EPSV 1e-6f

typedef unsigned short u16;
typedef __attribute__((ext_vector_type(8))) short bf16x8;
typedef __attribute__((ext_vector_type(4))) short bf16x4;
typedef __attribute__((ext_vector_type(4))) float f32x4;

__device__ __forceinline__ float bf2f(u16 u) {
  union { unsigned int i; float f; } x; x.i = ((unsigned int)u) << 16; return x.f;
}
__device__ __forceinline__ u16 f2bf(float f) {
  union { float f; unsigned int i; } x; x.f = f;
  unsigned int i = x.i;
  unsigned int r = i + 0x7FFFu + ((i >> 16) & 1u);   // round-to-nearest-even
  return (u16)(r >> 16);
}

typedef const __attribute__((address_space(1))) unsigned int* gas_p;
typedef __attribute__((address_space(3))) unsigned int* las_p;
__device__ __forceinline__ void gload16(const void* g, void* l) {
  __builtin_amdgcn_global_load_lds((gas_p)g, (las_p)l, 16, 0, 0);
}

// ================= persistent Sinkhorn, 16-way group barriers =================
// 256 wgs (16x16), each owns a 256x256 tile of K=exp(W) in LDS (1 wg/CU).
// Phase A (colsum) -> sync column-group {wg(*,b)}; Phase B (rowsum) -> sync
// row-group {wg(a,*)}. Partial buffers are parity double-buffered so the
// permitted 1-phase skew between groups cannot WAR-race.

#define SINK_WGS 256
#define SINK_SMEM (131072 + 1024 + 1024 + 8192)

__device__ __forceinline__ void gsync16(unsigned* ctr, int round) {
  __syncthreads();
  if (threadIdx.x == 0) {
    __threadfence();                       // release
    atomicAdd(ctr, 1u);
    unsigned goal = (unsigned)(round + 1) * 16u;
    long spin = 0;
    while (__hip_atomic_load(ctr, __ATOMIC_RELAXED, __HIP_MEMORY_SCOPE_AGENT) < goal &&
           ++spin < 2000000000L) {}
    __threadfence();                       // acquire
  }
  __syncthreads();
}

__global__ __launch_bounds__(512) void k_sinkhorn(
    const float* __restrict__ W, float* __restrict__ ubuf, float* __restrict__ vbuf,
    float* __restrict__ Spart, float* __restrict__ Tpart, unsigned* bar) {
  extern __shared__ char smem[];
  u16* Kt = (u16*)smem;                       // [256][256] bf16
  float* u_loc = (float*)(smem + 131072);     // [256]
  float* v_loc = u_loc + 256;                 // [256]
  float* red = v_loc + 256;                   // [8][256]

  int wg = blockIdx.x;
  int a = wg >> 4, b = wg & 15;               // row-stripe, col-stripe
  int i0 = a * 256, j0 = b * 256;
  int t = threadIdx.x;
  int lane = t & 63, wv = t >> 6;
  int cg = t & 31;

  unsigned* colbar = bar + b * 64;            // 16-way: wgs (*, b)
  unsigned* rowbar = bar + (16 + a) * 64;     // 16-way: wgs (a, *)

  // ---- stage exp(W) tile into LDS ----
#pragma unroll
  for (int k = 0; k < 32; ++k) {
    int q = t + 512 * k;
    int il = q >> 6;
    int jc = (q & 63) << 2;
    f32x4 wvv = *(const f32x4*)(W + (size_t)(i0 + il) * NN + (j0 + jc));
    bf16x4 r;
#pragma unroll
    for (int c = 0; c < 4; ++c) r[c] = (short)f2bf(expf(wvv[c]));
    *(bf16x4*)(Kt + il * 256 + jc) = r;
  }
  if (t < 256) { u_loc[t] = 1.f; v_loc[t] = 1.f; }
  __syncthreads();

  for (int it = 0; it < SINK_ITERS; ++it) {
    int par = (it & 1) * 16;
    // ===== Phase A: u update (from prev T partials) + partial colsum =====
    if (t < 256 && it > 0) {
      int pb = ((it - 1) & 1) * 16;
      float Ts = 0.f;
#pragma unroll
      for (int p = 0; p < 16; ++p) Ts += Tpart[(pb + p) * NN + i0 + t];
      float ul = u_loc[t];
      u_loc[t] = ul / (ul * Ts + EPSV);
    }
    __syncthreads();

    float acc[8] = {0.f, 0.f, 0.f, 0.f, 0.f, 0.f, 0.f, 0.f};
#pragma unroll
    for (int k = 0; k < 16; ++k) {
      int row = (t >> 5) + 16 * k;
      bf16x8 kv = *(const bf16x8*)(Kt + row * 256 + cg * 8);
      float ui = u_loc[row];
#pragma unroll
      for (int c = 0; c < 8; ++c) acc[c] += ui * bf2f((u16)kv[c]);
    }
#pragma unroll
    for (int c = 0; c < 8; ++c) acc[c] += __shfl_xor(acc[c], 32, 64);
    if (lane < 32) {
#pragma unroll
      for (int c = 0; c < 8; ++c) red[wv * 256 + cg * 8 + c] = acc[c];
    }
    __syncthreads();
    if (t < 256) {
      float s = 0.f;
#pragma unroll
      for (int w = 0; w < 8; ++w) s += red[w * 256 + t];
      Spart[(par + a) * NN + j0 + t] = s;
    }
    gsync16(colbar, it);

    // ===== Phase B: v update (from S partials) + partial rowsum =====
    if (t < 256) {
      float Ss = 0.f;
#pragma unroll
      for (int p = 0; p < 16; ++p) Ss += Spart[(par + p) * NN + j0 + t];
      float vo = v_loc[t];
      v_loc[t] = vo / (vo * Ss + EPSV);
    }
    __syncthreads();

    f32x4 va = *(const f32x4*)(v_loc + cg * 8);
    f32x4 vb2 = *(const f32x4*)(v_loc + cg * 8 + 4);
    float tr[16];
#pragma unroll
    for (int k = 0; k < 16; ++k) {
      int row = (t >> 5) + 16 * k;
      bf16x8 kv = *(const bf16x8*)(Kt + row * 256 + cg * 8);
      float s = 0.f;
#pragma unroll
      for (int c = 0; c < 4; ++c) s += bf2f((u16)kv[c]) * va[c];
#pragma unroll
      for (int c = 0; c < 4; ++c) s += bf2f((u16)kv[4 + c]) * vb2[c];
      tr[k] = s;
    }
#pragma unroll
    for (int k = 0; k < 16; ++k) {
#pragma unroll
      for (int d = 1; d <= 16; d <<= 1) tr[k] += __shfl_xor(tr[k], d, 64);
    }
    if (lane == 0 || lane == 32) {
#pragma unroll
      for (int k = 0; k < 16; ++k) red[(t >> 5) + 16 * k] = tr[k];
    }
    __syncthreads();
    if (t < 256) Tpart[(par + b) * NN + i0 + t] = red[t];
    gsync16(rowbar, it);
  }

  // ---- final u_20, v_20 ----
  if (t < 256) {
    int pb = ((SINK_ITERS - 1) & 1) * 16;
    float Ts = 0.f;
#pragma unroll
    for (int p = 0; p < 16; ++p) Ts += Tpart[(pb + p) * NN + i0 + t];
    float ul = u_loc[t];
    ul = ul / (ul * Ts + EPSV);
    if (b == 0) ubuf[i0 + t] = ul;
    if (a == 0) vbuf[j0 + t] = v_loc[t];
  }
}

// ================= legacy fallback path =================
__global__ void k_init(float* __restrict__ u, float* __restrict__ v,
                       float* __restrict__ S, float* __restrict__ T) {
  int i = blockIdx.x * 256 + threadIdx.x;
  if (i < NN) { u[i] = 1.f; v[i] = 1.f; S[i] = 0.f; T[i] = 0.f; }
}

__global__ void k_expbf(const float* __restrict__ W, u16* __restrict__ Kb) {
  long idx = ((long)blockIdx.x * 256 + threadIdx.x) * 8;
  f32x4 a = *(const f32x4*)(W + idx);
  f32x4 b = *(const f32x4*)(W + idx + 4);
  bf16x8 r;
#pragma unroll
  for (int c = 0; c < 4; ++c) r[c] = (short)f2bf(expf(a[c]));
#pragma unroll
  for (int c = 0; c < 4; ++c) r[4 + c] = (short)f2bf(expf(b[c]));
  *(bf16x8*)(Kb + idx) = r;
}

__global__ void k_f2bf(const float* __restrict__ X, u16* __restrict__ Xb, long n8) {
  long stride = (long)gridDim.x * blockDim.x;
  for (long i = (long)blockIdx.x * blockDim.x + threadIdx.x; i < n8; i += stride) {
    long idx = i * 8;
    f32x4 a = *(const f32x4*)(X + idx);
    f32x4 b = *(const f32x4*)(X + idx + 4);
    bf16x8 r;
#pragma unroll
    for (int c = 0; c < 4; ++c) r[c] = (short)f2bf(a[c]);
#pragma unroll
    for (int c = 0; c < 4; ++c) r[4 + c] = (short)f2bf(b[c]);
    *(bf16x8*)(Xb + idx) = r;
  }
}

__global__ void k_colsum(const u16* __restrict__ Kb, const float* __restrict__ u,
                         float* __restrict__ S) {
  int jb = blockIdx.x & 1, ib = blockIdx.x >> 1;
  int j0 = jb * 2048 + threadIdx.x * 8;
  int i0 = ib * 16;
  float acc[8] = {0.f, 0.f, 0.f, 0.f, 0.f, 0.f, 0.f, 0.f};
#pragma unroll
  for (int r = 0; r < 16; ++r) {
    int i = i0 + r;
    float ui = u[i];
    bf16x8 kv = *(const bf16x8*)(Kb + (size_t)i * NN + j0);
#pragma unroll
    for (int c = 0; c < 8; ++c) acc[c] += ui * bf2f((u16)kv[c]);
  }
#pragma unroll
  for (int c = 0; c < 8; ++c) atomicAdd(&S[j0 + c], acc[c]);
}

__global__ void k_rowsum(const u16* __restrict__ Kb, const float* __restrict__ v,
                         const float* __restrict__ S, float* __restrict__ T) {
  int warp = threadIdx.x >> 6, lane = threadIdx.x & 63;
  int row = blockIdx.x * 4 + warp;
  const u16* kr = Kb + (size_t)row * NN;
  float acc = 0.f;
#pragma unroll
  for (int itn = 0; itn < 8; ++itn) {
    int j = itn * 512 + lane * 8;
    bf16x8 kv = *(const bf16x8*)(kr + j);
    f32x4 v0 = *(const f32x4*)(v + j);
    f32x4 v1 = *(const f32x4*)(v + j + 4);
    f32x4 s0 = *(const f32x4*)(S + j);
    f32x4 s1 = *(const f32x4*)(S + j + 4);
#pragma unroll
    for (int c = 0; c < 4; ++c) acc += bf2f((u16)kv[c]) * (v0[c] / (v0[c] * s0[c] + EPSV));
#pragma unroll
    for (int c = 0; c < 4; ++c) acc += bf2f((u16)kv[4 + c]) * (v1[c] / (v1[c] * s1[c] + EPSV));
  }
#pragma unroll
  for (int off = 32; off > 0; off >>= 1) acc += __shfl_down(acc, off, 64);
  if (lane == 0) T[row] = acc;
}

__global__ void k_update(float* __restrict__ u, float* __restrict__ v,
                         float* __restrict__ S, float* __restrict__ T) {
  int i = blockIdx.x * 256 + threadIdx.x;
  if (i < NN) {
    float vi = v[i], Si = S[i];
    v[i] = vi / (vi * Si + EPSV);
    S[i] = 0.f;
    float ui = u[i], Ti = T[i];
    u[i] = ui / (ui * Ti + EPSV);
    T[i] = 0.f;
  }
}

// ---------------- Pt[j][i] = bf16(u_i * exp(W_ij) * v_j) ----------------
__global__ void k_matP(const float* __restrict__ W, const float* __restrict__ u,
                       const float* __restrict__ v, u16* __restrict__ Pt) {
  __shared__ float tile[64 * 65];
  int bx = blockIdx.x & 63, by = blockIdx.x >> 6;
  int tx = threadIdx.x & 63, ty = threadIdx.x >> 6;
  float vj = v[bx * 64 + tx];
#pragma unroll
  for (int r = 0; r < 16; ++r) {
    int il = r * 4 + ty;
    int i = by * 64 + il;
    float w = W[(size_t)i * NN + bx * 64 + tx];
    tile[il * 65 + tx] = u[i] * expf(w) * vj;
  }
  __syncthreads();
#pragma unroll
  for (int r = 0; r < 16; ++r) {
    int jl = r * 4 + ty;
    Pt[(size_t)(bx * 64 + jl) * NN + by * 64 + tx] = f2bf(tile[tx * 65 + jl]);
  }
}

// ---------------- GEMM: C[16384][4096] = A_bf16 @ Pt^T (m97 128x128) ----------------
#define BM 128
#define BN 128
#define BK 32
#define NT (NN / BK)

__global__ __launch_bounds__(256) void k_gemm(const u16* __restrict__ A,
                                              const u16* __restrict__ Bt,
                                              float* __restrict__ C) {
  __shared__ __align__(16) u16 lA[2][BM * BK];
  __shared__ __align__(16) u16 lB[2][BN * BK];

  int bid = blockIdx.x;
  int swz = (bid & 7) * 512 + (bid >> 3);
  int bm = swz >> 5, bn = swz & 31;

  int tid = threadIdx.x;
  int lane = tid & 63, w = tid >> 6;
  int wm = (w >> 1) * 64, wn = (w & 1) * 64;
  size_t m0 = (size_t)bm * BM, n0 = (size_t)bn * BN;

  f32x4 acc[4][4];
#pragma unroll
  for (int a = 0; a < 4; ++a)
#pragma unroll
    for (int b = 0; b < 4; ++b) acc[a][b] = (f32x4){0.f, 0.f, 0.f, 0.f};

  int srow = tid >> 2;
  int skc = (tid & 3) * 8;

  auto stage = [&](int buf, int t) {
    int k0 = t * BK;
#pragma unroll
    for (int it = 0; it < 2; ++it) {
      int row = it * 64 + srow;
      gload16(A + (m0 + row) * NN + k0 + skc, &lA[buf][row * BK + skc]);
      gload16(Bt + (n0 + row) * NN + k0 + skc, &lB[buf][row * BK + skc]);
    }
  };

  stage(0, 0);
  __syncthreads();

  int arow = wm + (lane & 15);
  int brow = wn + (lane & 15);
  int kc = (lane >> 4) * 8;

  for (int t = 0; t < NT; ++t) {
    int cur = t & 1;
    if (t < NT - 1) stage(cur ^ 1, t + 1);
    bf16x8 af[4], bfr[4];
#pragma unroll
    for (int f = 0; f < 4; ++f) {
      af[f] = *(const bf16x8*)&lA[cur][(arow + f * 16) * BK + kc];
      bfr[f] = *(const bf16x8*)&lB[cur][(brow + f * 16) * BK + kc];
    }
#pragma unroll
    for (int fm = 0; fm < 4; ++fm)
#pragma unroll
      for (int fn = 0; fn < 4; ++fn)
        acc[fm][fn] = __builtin_amdgcn_mfma_f32_16x16x32_bf16(af[fm], bfr[fn], acc[fm][fn], 0, 0, 0);
    __syncthreads();
  }

#pragma unroll
  for (int fm = 0; fm < 4; ++fm) {
    int r0 = wm + fm * 16 + (lane >> 4) * 4;
#pragma unroll
    for (int fn = 0; fn < 4; ++fn) {
      int c0 = wn + fn * 16 + (lane & 15);
#pragma unroll
      for (int i = 0; i < 4; ++i) {
        C[(m0 + r0 + i) * NN + n0 + c0] = acc[fm][fn][i];
      }
    }
  }
}

extern "C" void kernel_launch(void* const* d_in, const int* in_sizes, int n_in,
                              void* d_out, int out_size, void* d_ws, size_t ws_size,
                              hipStream_t stream) {
  const float* x = (const float*)d_in[0];   // [4,4096,4096] f32
  const float* W = (const float*)d_in[1];   // [4096,4096] f32
  float* out = (float*)d_out;               // [4,4096,4096] f32

  char* ws = (char*)d_ws;
  const size_t XB_OFF = 0;                      // 128 MB
  const size_t PT_OFF = 134217728;              // 32 MB
  const size_t KB_OFF = 167772160;              // 32 MB (legacy Kb / coop scratch)
  const size_t VEC_OFF = 201326592;             // legacy u,v,S,T
  if (ws_size < VEC_OFF + 4 * (size_t)NN * sizeof(float)) return;

  u16* xb = (u16*)(ws + XB_OFF);
  u16* Ptb = (u16*)(ws + PT_OFF);
  u16* Kb = (u16*)(ws + KB_OFF);
  float* lu = (float*)(ws + VEC_OFF);
  float* lv = lu + NN;
  float* lS = lv + NN;
  float* lT = lS + NN;

  // coop scratch overlaps the (unused-in-coop-path) Kb region
  float* ub = (float*)(ws + KB_OFF);            // [4096]
  float* vb = ub + NN;                          // [4096]
  float* Sp = vb + NN;                          // [2][16][4096]
  float* Tp = Sp + 32 * NN;                     // [2][16][4096]
  unsigned* bar = (unsigned*)(Tp + 32 * NN);    // [32][64] (256B-strided counters)

  k_f2bf<<<2048, 256, 0, stream>>>(x, xb, (long)out_size / 8);

  bool coop = true;
  int dev = 0;
  hipDeviceProp_t prop;
  if (hipGetDevice(&dev) != hipSuccess) coop = false;
  else if (hipGetDeviceProperties(&prop, dev) != hipSuccess) coop = false;
  else if (prop.multiProcessorCount < SINK_WGS) coop = false;
  if (coop && hipFuncSetAttribute((const void*)k_sinkhorn,
                                  hipFuncAttributeMaxDynamicSharedMemorySize,
                                  SINK_SMEM) != hipSuccess)
    coop = false;

  if (coop) {
    hipMemsetAsync(bar, 0, 32 * 64 * sizeof(unsigned), stream);
    k_sinkhorn<<<SINK_WGS, 512, SINK_SMEM, stream>>>(W, ub, vb, Sp, Tp, bar);
    if (hipGetLastError() != hipSuccess) coop = false;
  }

  const float* uP;
  const float* vP;
  if (coop) {
    uP = ub;
    vP = vb;
  } else {
    k_init<<<16, 256, 0, stream>>>(lu, lv, lS, lT);
    k_expbf<<<8192, 256, 0, stream>>>(W, Kb);
    for (int it = 0; it < SINK_ITERS; ++it) {
      k_colsum<<<512, 256, 0, stream>>>(Kb, lu, lS);
      k_rowsum<<<1024, 256, 0, stream>>>(Kb, lv, lS, lT);
      k_update<<<16, 256, 0, stream>>>(lu, lv, lS, lT);
    }
    uP = lu;
    vP = lv;
  }

  k_matP<<<4096, 256, 0, stream>>>(W, uP, vP, Ptb);
  k_gemm<<<4096, 256, 0, stream>>>(xb, Ptb, out);
}

// Round 4
// 1098.647 us; speedup vs baseline: 2.1605x; 1.2264x over previous
//
#include <hip/hip_runtime.h>
#include <hip/hip_bf16.h>
#include <cstdint>
#include <cstddef>

#define NN 4096
#define SINK_ITERS 20
#define EPSV 1e-6f

typedef unsigned short u16;
typedef __attribute__((ext_vector_type(8))) short bf16x8;
typedef __attribute__((ext_vector_type(4))) short bf16x4;
typedef __attribute__((ext_vector_type(4))) float f32x4;

__device__ __forceinline__ float bf2f(u16 u) {
  union { unsigned int i; float f; } x; x.i = ((unsigned int)u) << 16; return x.f;
}
__device__ __forceinline__ u16 f2bf(float f) {
  union { float f; unsigned int i; } x; x.f = f;
  unsigned int i = x.i;
  unsigned int r = i + 0x7FFFu + ((i >> 16) & 1u);   // round-to-nearest-even
  return (u16)(r >> 16);
}

typedef const __attribute__((address_space(1))) unsigned int* gas_p;
typedef __attribute__((address_space(3))) unsigned int* las_p;
__device__ __forceinline__ void gload16(const void* g, void* l) {
  __builtin_amdgcn_global_load_lds((gas_p)g, (las_p)l, 16, 0, 0);
}

// ================= persistent Sinkhorn, 16-way group barriers =================
#define SINK_WGS 256
#define SINK_SMEM (131072 + 1024 + 1024 + 8192)

__device__ __forceinline__ void gsync16(unsigned* ctr, int round) {
  __syncthreads();
  if (threadIdx.x == 0) {
    __threadfence();
    atomicAdd(ctr, 1u);
    unsigned goal = (unsigned)(round + 1) * 16u;
    long spin = 0;
    while (__hip_atomic_load(ctr, __ATOMIC_RELAXED, __HIP_MEMORY_SCOPE_AGENT) < goal &&
           ++spin < 2000000000L) {}
    __threadfence();
  }
  __syncthreads();
}

__global__ __launch_bounds__(512) void k_sinkhorn(
    const float* __restrict__ W, float* __restrict__ ubuf, float* __restrict__ vbuf,
    float* __restrict__ Spart, float* __restrict__ Tpart, unsigned* bar) {
  extern __shared__ char smem[];
  u16* Kt = (u16*)smem;                       // [256][256] bf16
  float* u_loc = (float*)(smem + 131072);     // [256]
  float* v_loc = u_loc + 256;                 // [256]
  float* red = v_loc + 256;                   // [8][256]

  int wg = blockIdx.x;
  int a = wg >> 4, b = wg & 15;
  int i0 = a * 256, j0 = b * 256;
  int t = threadIdx.x;
  int lane = t & 63, wv = t >> 6;
  int cg = t & 31;

  unsigned* colbar = bar + b * 64;
  unsigned* rowbar = bar + (16 + a) * 64;

#pragma unroll
  for (int k = 0; k < 32; ++k) {
    int q = t + 512 * k;
    int il = q >> 6;
    int jc = (q & 63) << 2;
    f32x4 wvv = *(const f32x4*)(W + (size_t)(i0 + il) * NN + (j0 + jc));
    bf16x4 r;
#pragma unroll
    for (int c = 0; c < 4; ++c) r[c] = (short)f2bf(expf(wvv[c]));
    *(bf16x4*)(Kt + il * 256 + jc) = r;
  }
  if (t < 256) { u_loc[t] = 1.f; v_loc[t] = 1.f; }
  __syncthreads();

  for (int it = 0; it < SINK_ITERS; ++it) {
    int par = (it & 1) * 16;
    if (t < 256 && it > 0) {
      int pb = ((it - 1) & 1) * 16;
      float Ts = 0.f;
#pragma unroll
      for (int p = 0; p < 16; ++p) Ts += Tpart[(pb + p) * NN + i0 + t];
      float ul = u_loc[t];
      u_loc[t] = ul / (ul * Ts + EPSV);
    }
    __syncthreads();

    float acc[8] = {0.f, 0.f, 0.f, 0.f, 0.f, 0.f, 0.f, 0.f};
#pragma unroll
    for (int k = 0; k < 16; ++k) {
      int row = (t >> 5) + 16 * k;
      bf16x8 kv = *(const bf16x8*)(Kt + row * 256 + cg * 8);
      float ui = u_loc[row];
#pragma unroll
      for (int c = 0; c < 8; ++c) acc[c] += ui * bf2f((u16)kv[c]);
    }
#pragma unroll
    for (int c = 0; c < 8; ++c) acc[c] += __shfl_xor(acc[c], 32, 64);
    if (lane < 32) {
#pragma unroll
      for (int c = 0; c < 8; ++c) red[wv * 256 + cg * 8 + c] = acc[c];
    }
    __syncthreads();
    if (t < 256) {
      float s = 0.f;
#pragma unroll
      for (int w = 0; w < 8; ++w) s += red[w * 256 + t];
      Spart[(par + a) * NN + j0 + t] = s;
    }
    gsync16(colbar, it);

    if (t < 256) {
      float Ss = 0.f;
#pragma unroll
      for (int p = 0; p < 16; ++p) Ss += Spart[(par + p) * NN + j0 + t];
      float vo = v_loc[t];
      v_loc[t] = vo / (vo * Ss + EPSV);
    }
    __syncthreads();

    f32x4 va = *(const f32x4*)(v_loc + cg * 8);
    f32x4 vb2 = *(const f32x4*)(v_loc + cg * 8 + 4);
    float tr[16];
#pragma unroll
    for (int k = 0; k < 16; ++k) {
      int row = (t >> 5) + 16 * k;
      bf16x8 kv = *(const bf16x8*)(Kt + row * 256 + cg * 8);
      float s = 0.f;
#pragma unroll
      for (int c = 0; c < 4; ++c) s += bf2f((u16)kv[c]) * va[c];
#pragma unroll
      for (int c = 0; c < 4; ++c) s += bf2f((u16)kv[4 + c]) * vb2[c];
      tr[k] = s;
    }
#pragma unroll
    for (int k = 0; k < 16; ++k) {
#pragma unroll
      for (int d = 1; d <= 16; d <<= 1) tr[k] += __shfl_xor(tr[k], d, 64);
    }
    if (lane == 0 || lane == 32) {
#pragma unroll
      for (int k = 0; k < 16; ++k) red[(t >> 5) + 16 * k] = tr[k];
    }
    __syncthreads();
    if (t < 256) Tpart[(par + b) * NN + i0 + t] = red[t];
    gsync16(rowbar, it);
  }

  if (t < 256) {
    int pb = ((SINK_ITERS - 1) & 1) * 16;
    float Ts = 0.f;
#pragma unroll
    for (int p = 0; p < 16; ++p) Ts += Tpart[(pb + p) * NN + i0 + t];
    float ul = u_loc[t];
    ul = ul / (ul * Ts + EPSV);
    if (b == 0) ubuf[i0 + t] = ul;
    if (a == 0) vbuf[j0 + t] = v_loc[t];
  }
}

// ================= helpers =================
__global__ void k_f2bf(const float* __restrict__ X, u16* __restrict__ Xb, long n8) {
  long stride = (long)gridDim.x * blockDim.x;
  for (long i = (long)blockIdx.x * blockDim.x + threadIdx.x; i < n8; i += stride) {
    long idx = i * 8;
    f32x4 a = *(const f32x4*)(X + idx);
    f32x4 b = *(const f32x4*)(X + idx + 4);
    bf16x8 r;
#pragma unroll
    for (int c = 0; c < 4; ++c) r[c] = (short)f2bf(a[c]);
#pragma unroll
    for (int c = 0; c < 4; ++c) r[4 + c] = (short)f2bf(b[c]);
    *(bf16x8*)(Xb + idx) = r;
  }
}

// ---------------- Pt[j][i] = bf16(u_i * exp(W_ij) * v_j) ----------------
__global__ void k_matP(const float* __restrict__ W, const float* __restrict__ u,
                       const float* __restrict__ v, u16* __restrict__ Pt) {
  __shared__ float tile[64 * 65];
  int bx = blockIdx.x & 63, by = blockIdx.x >> 6;
  int tx = threadIdx.x & 63, ty = threadIdx.x >> 6;
  float vj = v[bx * 64 + tx];
#pragma unroll
  for (int r = 0; r < 16; ++r) {
    int il = r * 4 + ty;
    int i = by * 64 + il;
    float w = W[(size_t)i * NN + bx * 64 + tx];
    tile[il * 65 + tx] = u[i] * expf(w) * vj;
  }
  __syncthreads();
#pragma unroll
  for (int r = 0; r < 16; ++r) {
    int jl = r * 4 + ty;
    Pt[(size_t)(bx * 64 + jl) * NN + by * 64 + tx] = f2bf(tile[tx * 65 + jl]);
  }
}

// ================= GEMM 256x256 / BK=64 / 8 waves, swizzled LDS =================
#define GBM 256
#define GBN 256
#define GBK 64
#define GNT (NN / GBK)
#define GEMM_SMEM 131072

// swizzled ds_read of one MFMA A/B fragment (16 rows x 8 k) from a k-slab
#define RD_FRAG(base, R) \
  (*(const bf16x8*)((base) + (R) * 64 + (kgb ^ ((((R) >> 3) & 1) << 5))))

__global__ __launch_bounds__(512, 2) void k_gemm256(const u16* __restrict__ A,
                                                    const u16* __restrict__ Bt,
                                                    float* __restrict__ C) {
  extern __shared__ __align__(1024) char gsm[];

  int bid = blockIdx.x;              // 1024 blocks
  int xcd = bid & 7, sidx = bid >> 3;
  int bm = (xcd << 3) | (sidx >> 4); // 0..63 (M stripe per XCD)
  int bn = sidx & 15;                // 0..15
  size_t m0 = (size_t)bm * GBM, n0 = (size_t)bn * GBN;

  int tid = threadIdx.x;
  int lane = tid & 63, w = tid >> 6;
  int wm = w >> 2, wn = w & 3;       // 2 x 4 waves -> 128x64 per wave
  int l15 = lane & 15, kgb = (lane >> 4) * 16;

  // staging: 4 x 16B per thread per matrix; linear LDS dest, inverse-swizzled src
  int srcA[4], srcB[4], dstb[4];
#pragma unroll
  for (int i = 0; i < 4; ++i) {
    int d = (i * 512 + tid) * 16;
    int L = d ^ (((d >> 9) & 1) << 5);
    int ss = L >> 14, rr = (L >> 6) & 255, cc = (L & 63) >> 1;
    dstb[i] = d;
    srcA[i] = (int)((m0 + rr) * NN) + ss * 32 + cc;
    srcB[i] = (int)((n0 + rr) * NN) + ss * 32 + cc;
  }

  f32x4 acc[8][4];
#pragma unroll
  for (int m = 0; m < 8; ++m)
#pragma unroll
    for (int n = 0; n < 4; ++n) acc[m][n] = (f32x4){0.f, 0.f, 0.f, 0.f};

#define STAGE(BUF, T)                                                         \
  {                                                                           \
    int k0_ = (T) * GBK;                                                      \
    char* la_ = gsm + (BUF) * 65536;                                          \
    char* lb_ = la_ + 32768;                                                  \
    _Pragma("unroll")                                                         \
    for (int i = 0; i < 4; ++i) gload16(A + (size_t)srcA[i] + k0_, la_ + dstb[i]); \
    _Pragma("unroll")                                                         \
    for (int i = 0; i < 4; ++i) gload16(Bt + (size_t)srcB[i] + k0_, lb_ + dstb[i]); \
  }

  STAGE(0, 0)

  for (int t = 0; t < GNT; ++t) {
    int cur = t & 1;
    asm volatile("s_waitcnt vmcnt(0)" ::: "memory");  // tile t's stages landed
    __syncthreads();                                   // all waves ready; prev buf free
    if (t + 1 < GNT) STAGE(cur ^ 1, t + 1)             // in flight across whole tile

    const char* ta0 = gsm + cur * 65536;
    const char* ta1 = ta0 + 16384;
    const char* tb0 = ta0 + 32768;
    const char* tb1 = tb0 + 16384;

    bf16x8 af[4][2], bfr[2][2][2];

    // ---- P1: mh=0, nh=0 ----
#pragma unroll
    for (int fm = 0; fm < 4; ++fm) {
      int r = wm * 128 + fm * 16 + l15;
      af[fm][0] = RD_FRAG(ta0, r);
      af[fm][1] = RD_FRAG(ta1, r);
    }
#pragma unroll
    for (int fn = 0; fn < 2; ++fn) {
      int r = wn * 64 + fn * 16 + l15;
      bfr[0][fn][0] = RD_FRAG(tb0, r);
      bfr[0][fn][1] = RD_FRAG(tb1, r);
    }
    __builtin_amdgcn_s_setprio(1);
#pragma unroll
    for (int fm = 0; fm < 4; ++fm)
#pragma unroll
      for (int fn = 0; fn < 2; ++fn) {
        acc[fm][fn] = __builtin_amdgcn_mfma_f32_16x16x32_bf16(af[fm][0], bfr[0][fn][0], acc[fm][fn], 0, 0, 0);
        acc[fm][fn] = __builtin_amdgcn_mfma_f32_16x16x32_bf16(af[fm][1], bfr[0][fn][1], acc[fm][fn], 0, 0, 0);
      }
    __builtin_amdgcn_s_setprio(0);

    // ---- P2: mh=0, nh=1 (load B1, reuse A) ----
#pragma unroll
    for (int fn = 0; fn < 2; ++fn) {
      int r = wn * 64 + 32 + fn * 16 + l15;
      bfr[1][fn][0] = RD_FRAG(tb0, r);
      bfr[1][fn][1] = RD_FRAG(tb1, r);
    }
    __builtin_amdgcn_s_setprio(1);
#pragma unroll
    for (int fm = 0; fm < 4; ++fm)
#pragma unroll
      for (int fn = 0; fn < 2; ++fn) {
        acc[fm][2 + fn] = __builtin_amdgcn_mfma_f32_16x16x32_bf16(af[fm][0], bfr[1][fn][0], acc[fm][2 + fn], 0, 0, 0);
        acc[fm][2 + fn] = __builtin_amdgcn_mfma_f32_16x16x32_bf16(af[fm][1], bfr[1][fn][1], acc[fm][2 + fn], 0, 0, 0);
      }
    __builtin_amdgcn_s_setprio(0);

    // ---- P3: mh=1, nh=1 (load A-half1, reuse B1) ----
#pragma unroll
    for (int fm = 0; fm < 4; ++fm) {
      int r = wm * 128 + 64 + fm * 16 + l15;
      af[fm][0] = RD_FRAG(ta0, r);
      af[fm][1] = RD_FRAG(ta1, r);
    }
    __builtin_amdgcn_s_setprio(1);
#pragma unroll
    for (int fm = 0; fm < 4; ++fm)
#pragma unroll
      for (int fn = 0; fn < 2; ++fn) {
        acc[4 + fm][2 + fn] = __builtin_amdgcn_mfma_f32_16x16x32_bf16(af[fm][0], bfr[1][fn][0], acc[4 + fm][2 + fn], 0, 0, 0);
        acc[4 + fm][2 + fn] = __builtin_amdgcn_mfma_f32_16x16x32_bf16(af[fm][1], bfr[1][fn][1], acc[4 + fm][2 + fn], 0, 0, 0);
      }
    __builtin_amdgcn_s_setprio(0);

    // ---- P4: mh=1, nh=0 (reuse A-half1, reuse B0) ----
    __builtin_amdgcn_s_setprio(1);
#pragma unroll
    for (int fm = 0; fm < 4; ++fm)
#pragma unroll
      for (int fn = 0; fn < 2; ++fn) {
        acc[4 + fm][fn] = __builtin_amdgcn_mfma_f32_16x16x32_bf16(af[fm][0], bfr[0][fn][0], acc[4 + fm][fn], 0, 0, 0);
        acc[4 + fm][fn] = __builtin_amdgcn_mfma_f32_16x16x32_bf16(af[fm][1], bfr[0][fn][1], acc[4 + fm][fn], 0, 0, 0);
      }
    __builtin_amdgcn_s_setprio(0);
  }

  // ---- epilogue ----
#pragma unroll
  for (int m = 0; m < 8; ++m) {
    size_t gr = m0 + (size_t)wm * 128 + m * 16 + (lane >> 4) * 4;
#pragma unroll
    for (int n = 0; n < 4; ++n) {
      size_t gc = n0 + (size_t)wn * 64 + n * 16 + l15;
#pragma unroll
      for (int i = 0; i < 4; ++i)
        C[(gr + i) * NN + gc] = acc[m][n][i];
    }
  }
#undef STAGE
}

// ---------------- legacy 128x128 GEMM (fallback) ----------------
#define BM 128
#define BN 128
#define BK 32
#define NT (NN / BK)

__global__ __launch_bounds__(256) void k_gemm(const u16* __restrict__ A,
                                              const u16* __restrict__ Bt,
                                              float* __restrict__ C) {
  __shared__ __align__(16) u16 lA[2][BM * BK];
  __shared__ __align__(16) u16 lB[2][BN * BK];

  int bid = blockIdx.x;
  int swz = (bid & 7) * 512 + (bid >> 3);
  int bm = swz >> 5, bn = swz & 31;

  int tid = threadIdx.x;
  int lane = tid & 63, w = tid >> 6;
  int wm = (w >> 1) * 64, wn = (w & 1) * 64;
  size_t m0 = (size_t)bm * BM, n0 = (size_t)bn * BN;

  f32x4 acc[4][4];
#pragma unroll
  for (int a = 0; a < 4; ++a)
#pragma unroll
    for (int b = 0; b < 4; ++b) acc[a][b] = (f32x4){0.f, 0.f, 0.f, 0.f};

  int srow = tid >> 2;
  int skc = (tid & 3) * 8;

  auto stage = [&](int buf, int t) {
    int k0 = t * BK;
#pragma unroll
    for (int it = 0; it < 2; ++it) {
      int row = it * 64 + srow;
      gload16(A + (m0 + row) * NN + k0 + skc, &lA[buf][row * BK + skc]);
      gload16(Bt + (n0 + row) * NN + k0 + skc, &lB[buf][row * BK + skc]);
    }
  };

  stage(0, 0);
  __syncthreads();

  int arow = wm + (lane & 15);
  int brow = wn + (lane & 15);
  int kc = (lane >> 4) * 8;

  for (int t = 0; t < NT; ++t) {
    int cur = t & 1;
    if (t < NT - 1) stage(cur ^ 1, t + 1);
    bf16x8 af[4], bfr[4];
#pragma unroll
    for (int f = 0; f < 4; ++f) {
      af[f] = *(const bf16x8*)&lA[cur][(arow + f * 16) * BK + kc];
      bfr[f] = *(const bf16x8*)&lB[cur][(brow + f * 16) * BK + kc];
    }
#pragma unroll
    for (int fm = 0; fm < 4; ++fm)
#pragma unroll
      for (int fn = 0; fn < 4; ++fn)
        acc[fm][fn] = __builtin_amdgcn_mfma_f32_16x16x32_bf16(af[fm], bfr[fn], acc[fm][fn], 0, 0, 0);
    __syncthreads();
  }

#pragma unroll
  for (int fm = 0; fm < 4; ++fm) {
    int r0 = wm + fm * 16 + (lane >> 4) * 4;
#pragma unroll
    for (int fn = 0; fn < 4; ++fn) {
      int c0 = wn + fn * 16 + (lane & 15);
#pragma unroll
      for (int i = 0; i < 4; ++i) {
        C[(m0 + r0 + i) * NN + n0 + c0] = acc[fm][fn][i];
      }
    }
  }
}

extern "C" void kernel_launch(void* const* d_in, const int* in_sizes, int n_in,
                              void* d_out, int out_size, void* d_ws, size_t ws_size,
                              hipStream_t stream) {
  const float* x = (const float*)d_in[0];   // [4,4096,4096] f32
  const float* W = (const float*)d_in[1];   // [4096,4096] f32
  float* out = (float*)d_out;               // [4,4096,4096] f32

  char* ws = (char*)d_ws;
  const size_t XB_OFF = 0;                      // 128 MB
  const size_t PT_OFF = 134217728;              // 32 MB
  const size_t KB_OFF = 167772160;              // 32 MB coop scratch
  const size_t VEC_OFF = 201326592;
  if (ws_size < VEC_OFF + 4 * (size_t)NN * sizeof(float)) return;

  u16* xb = (u16*)(ws + XB_OFF);
  u16* Ptb = (u16*)(ws + PT_OFF);

  float* ub = (float*)(ws + KB_OFF);            // [4096]
  float* vb = ub + NN;                          // [4096]
  float* Sp = vb + NN;                          // [2][16][4096]
  float* Tp = Sp + 32 * NN;                     // [2][16][4096]
  unsigned* bar = (unsigned*)(Tp + 32 * NN);    // [32][64]

  k_f2bf<<<2048, 256, 0, stream>>>(x, xb, (long)out_size / 8);

  // ---- Sinkhorn (persistent; requires >= 256 CUs + 141KB LDS) ----
  bool coop = true;
  int dev = 0;
  hipDeviceProp_t prop;
  if (hipGetDevice(&dev) != hipSuccess) coop = false;
  else if (hipGetDeviceProperties(&prop, dev) != hipSuccess) coop = false;
  else if (prop.multiProcessorCount < SINK_WGS) coop = false;
  if (coop && hipFuncSetAttribute((const void*)k_sinkhorn,
                                  hipFuncAttributeMaxDynamicSharedMemorySize,
                                  SINK_SMEM) != hipSuccess)
    coop = false;

  if (coop) {
    hipMemsetAsync(bar, 0, 32 * 64 * sizeof(unsigned), stream);
    k_sinkhorn<<<SINK_WGS, 512, SINK_SMEM, stream>>>(W, ub, vb, Sp, Tp, bar);
    if (hipGetLastError() != hipSuccess) coop = false;
  }
  if (!coop) return;  // MI355X always satisfies the checks; hard dependency

  k_matP<<<4096, 256, 0, stream>>>(W, ub, vb, Ptb);

  // ---- GEMM: prefer 256^2 deep-pipelined kernel, fallback to 128^2 ----
  bool big = (hipFuncSetAttribute((const void*)k_gemm256,
                                  hipFuncAttributeMaxDynamicSharedMemorySize,
                                  GEMM_SMEM) == hipSuccess);
  if (big) {
    k_gemm256<<<1024, 512, GEMM_SMEM, stream>>>(xb, Ptb, out);
    if (hipGetLastError() != hipSuccess) big = false;
  }
  if (!big) k_gemm<<<4096, 256, 0, stream>>>(xb, Ptb, out);
}